// Round 1
// 900.746 us; speedup vs baseline: 1.0635x; 1.0635x over previous
//
#include <hip/hip_runtime.h>
#include <hip/hip_bf16.h>
#include <math.h>

#define BATCH 32
#define NTOK 577
#define DIM 768
#define NHEAD 12
#define HDIM 64
#define MLP 3072
#define ROWS (BATCH*NTOK)
#define ATTN_SCALE 0.125f
#define LN_EPS 1e-6f
#define VST 584
#define RST 584
#define TK 64
#define NRT 145   // row tiles of 128 over 18464 rows
#define SOFF 20.0f

typedef unsigned short u16;
typedef unsigned int u32;
typedef __attribute__((ext_vector_type(8))) short bf16x8;
typedef __attribute__((ext_vector_type(4))) float f32x4;

__device__ inline u16 f2bf(float f){
  u32 u = __float_as_uint(f);
  u32 r = (u + 0x7fffu + ((u>>16)&1u)) >> 16;
  return (u16)r;
}
__device__ inline float bf2f(u16 v){
  u32 u = ((u32)v)<<16; return __uint_as_float(u);
}

__device__ __forceinline__ void gload16(const u16* g, u16* l){
  __builtin_amdgcn_global_load_lds((const __attribute__((address_space(1))) void*)g,
                                   (__attribute__((address_space(3))) void*)l, 16, 0, 0);
}

// exact-erf GELU via A&S 7.1.26 rational approx (|err| < 1.5e-7)
__device__ inline float gelu_f(float v){
  float xa = fabsf(v)*0.70710678118654752f;
  float t = 1.0f/(1.0f + 0.3275911f*xa);
  float p = (((1.061405429f*t - 1.453152027f)*t + 1.421413741f)*t - 0.284496736f)*t + 0.254829592f;
  float erfv = 1.0f - p*t*__expf(-xa*xa);
  erfv = (v < 0.f) ? -erfv : erfv;
  return 0.5f*v*(1.0f + erfv);
}

// ---- fused weight conversion f32 -> bf16 ----
__global__ void cvt4_kernel(const float* __restrict__ s0, int n0,
                            const float* __restrict__ s1, int n1,
                            const float* __restrict__ s2, int n2,
                            const float* __restrict__ s3, int n3,
                            u16* __restrict__ d0, u16* __restrict__ d1,
                            u16* __restrict__ d2, u16* __restrict__ d3){
  int i = blockIdx.x*256 + threadIdx.x;
  if(i < n0){ d0[i] = f2bf(s0[i]); return; }
  i -= n0;
  if(i < n1){ d1[i] = f2bf(s1[i]); return; }
  i -= n1;
  if(i < n2){ d2[i] = f2bf(s2[i]); return; }
  i -= n2;
  if(i < n3){ d3[i] = f2bf(s3[i]); }
}

// ---- rpb precompute (bf16, padded row stride 584) ----
__global__ void rpb_kernel(const int* __restrict__ rel, const float* __restrict__ table, u16* __restrict__ bias){
  int i = blockIdx.x*256 + threadIdx.x;
  const int nm = NTOK*NTOK;
  if(i >= NHEAD*nm) return;
  int h = i / nm;
  int r = i - h*nm;
  int n = r / NTOK, m = r - n*NTOK;
  bias[((size_t)h*NTOK + n)*RST + m] = f2bf(table[rel[r]*NHEAD + h]);
}

// ---- LayerNorm ----
__global__ __launch_bounds__(256) void ln_kernel(const float* __restrict__ in, const float* __restrict__ g,
                                                 const float* __restrict__ b, u16* __restrict__ out){
  int row = blockIdx.x;
  const float* p = in + (size_t)row*DIM;
  int t = threadIdx.x;
  float v0 = p[t], v1 = p[t+256], v2 = p[t+512];
  float s = v0+v1+v2;
  #pragma unroll
  for(int off=32; off; off>>=1) s += __shfl_xor(s, off);
  __shared__ float red[8];
  int wv = t>>6;
  if((t&63)==0) red[wv] = s;
  __syncthreads();
  float mean = (red[0]+red[1]+red[2]+red[3]) * (1.0f/768.0f);
  float d0=v0-mean, d1=v1-mean, d2=v2-mean;
  float q = d0*d0 + d1*d1 + d2*d2;
  #pragma unroll
  for(int off=32; off; off>>=1) q += __shfl_xor(q, off);
  if((t&63)==0) red[4+wv] = q;
  __syncthreads();
  float var = (red[4]+red[5]+red[6]+red[7]) * (1.0f/768.0f);
  float inv = rsqrtf(var + LN_EPS);
  u16* po = out + (size_t)row*DIM;
  po[t]     = f2bf(d0*inv*g[t]     + b[t]);
  po[t+256] = f2bf(d1*inv*g[t+256] + b[t+256]);
  po[t+512] = f2bf(d2*inv*g[t+512] + b[t+512]);
}

// ---- 2-phase double-buffered staging helpers (compile-time buffer index
// at every call site so alias analysis can prove ds_read(buf) is independent
// of the in-flight global_load_lds into buf^1 -> no defensive vmcnt(0)
// before the MFMA phase) ----
__device__ __forceinline__ void stage32(const u16* __restrict__ Ab, const u16* __restrict__ Bb,
                                        int K, int koff,
                                        u16 (&Asb)[128][32], u16 (&Bsb)[128][32], int wave){
  gload16(Ab + koff,                &Asb[wave*32][0]);
  gload16(Ab + (size_t)16*K + koff, &Asb[wave*32 + 16][0]);
  gload16(Bb + koff,                &Bsb[wave*32][0]);
  gload16(Bb + (size_t)16*K + koff, &Bsb[wave*32 + 16][0]);
}

__device__ __forceinline__ void comp32(const u16 (&Asb)[128][32], const u16 (&Bsb)[128][32],
                                       int wr, int wc, int lrow, int lk, f32x4 (&acc)[4][4]){
  bf16x8 af[4], bfr[4];
  #pragma unroll
  for(int i=0;i<4;i++) af[i]  = *(const bf16x8*)(&Asb[wr + i*16 + lrow][lk]);
  #pragma unroll
  for(int j=0;j<4;j++) bfr[j] = *(const bf16x8*)(&Bsb[wc + j*16 + lrow][lk]);
  #pragma unroll
  for(int i=0;i<4;i++)
    #pragma unroll
    for(int j=0;j<4;j++)
      acc[i][j] = __builtin_amdgcn_mfma_f32_16x16x32_bf16(af[i], bfr[j], acc[i][j], 0,0,0);
}

// ---- 128x128 bf16 MFMA GEMM, 2-phase double-buffered pipeline:
// prefetch K-tile t+1 (global_load_lds) into the alternate 32-wide LDS buffer
// WHILE computing tile t; one barrier per 32-K tile. Loads get the full MFMA
// phase to land before the barrier's vmcnt drain (vs the old stage->barrier->
// compute structure that exposed full load latency at every barrier).
// glds staging, XCD-aware tile mapping. ----
template<int MODE, int NC>
__global__ __launch_bounds__(256) void gemm_kernel(
    const u16* __restrict__ A, const u16* __restrict__ Bt,
    int M, int K,
    const float* __restrict__ b0, const float* __restrict__ b1,
    const float* __restrict__ resid, float* __restrict__ outf,
    u16* __restrict__ o0, u16* __restrict__ o1, u16* __restrict__ o2)
{
  int id = blockIdx.x;
  int xcd = id & 7, sblk = id >> 3;
  int rg = sblk / NC, c = sblk - rg*NC;
  int r = xcd + 8*rg;
  if(r >= NRT) return;
  const int rowTile = r*128, colTile = c*128;

  __shared__ __align__(16) u16 As[2][128][32];
  __shared__ __align__(16) u16 Bs[2][128][32];
  const int tx = threadIdx.x;
  const int wave = tx>>6, lane = tx&63;
  const int wr = (wave>>1)*64, wc = (wave&1)*64;
  const int lrow = lane&15, lk = (lane>>4)*8;
  const int glr = lane>>2, glc = (lane&3)*8;   // 1KB glds: 16 rows x 32 cols
  f32x4 acc[4][4];
  #pragma unroll
  for(int i=0;i<4;i++)
    #pragma unroll
    for(int j=0;j<4;j++){ f32x4 z = {0.f,0.f,0.f,0.f}; acc[i][j]=z; }

  const u16* Abase = A + (size_t)(rowTile + wave*32 + glr)*K + glc;
  const u16* Bbase = Bt + (size_t)(colTile + wave*32 + glr)*K + glc;

  // prologue: stage first 32-K tile into buf0
  stage32(Abase, Bbase, K, 0, As[0], Bs[0], wave);
  __syncthreads();

  int kk = 0;
  for(; kk + 64 < K; kk += 64){
    stage32(Abase, Bbase, K, kk+32, As[1], Bs[1], wave);   // prefetch t+1
    comp32(As[0], Bs[0], wr, wc, lrow, lk, acc);           // compute t
    __syncthreads();
    stage32(Abase, Bbase, K, kk+64, As[0], Bs[0], wave);   // prefetch t+2
    comp32(As[1], Bs[1], wr, wc, lrow, lk, acc);           // compute t+1
    __syncthreads();
  }
  // epilogue of pipeline: kk == K-64 here (K is a multiple of 64)
  stage32(Abase, Bbase, K, kk+32, As[1], Bs[1], wave);
  comp32(As[0], Bs[0], wr, wc, lrow, lk, acc);
  __syncthreads();
  comp32(As[1], Bs[1], wr, wc, lrow, lk, acc);

  #pragma unroll
  for(int i=0;i<4;i++){
    int rbase = rowTile + wr + i*16 + (lane>>4)*4;
    #pragma unroll
    for(int j=0;j<4;j++){
      int col = colTile + wc + j*16 + (lane&15);
      #pragma unroll
      for(int rr=0; rr<4; rr++){
        int rrow = rbase + rr;
        if(rrow >= M) continue;
        float v = acc[i][j][rr];
        if(MODE==0){
          int part = col/DIM, cc = col - part*DIM;
          int head = cc>>6, d = cc&63;
          int bb = rrow/NTOK, n = rrow - bb*NTOK;
          size_t bh = (size_t)bb*NHEAD + head;
          if(part==0){ v = (v + b0[cc])*ATTN_SCALE; o0[(bh*NTOK + n)*HDIM + d] = f2bf(v); }
          else if(part==1){ o1[(bh*NTOK + n)*HDIM + d] = f2bf(v); }
          else { v += b1[cc]; o2[(bh*HDIM + d)*VST + n] = f2bf(v); }
        } else if(MODE==1){
          outf[(size_t)rrow*DIM + col] = v + b0[col] + resid[(size_t)rrow*DIM + col];
        } else if(MODE==2){
          o0[(size_t)rrow*MLP + col] = f2bf(gelu_f(v + b0[col]));
        } else {
          outf[(size_t)rrow*DIM + col] = v + b0[col] + resid[(size_t)rrow*DIM + col];
        }
      }
    }
  }
}

// ---- flash attention, no-max softmax (scores bounded; exp(s-SOFF) safe) ----
__global__ __launch_bounds__(256) void fattn_kernel(
    const u16* __restrict__ q, const u16* __restrict__ k, const u16* __restrict__ vt,
    const u16* __restrict__ rpb, u16* __restrict__ out)
{
  int bid = blockIdx.x;
  int qt = bid / 384;
  int rem = bid - qt*384;
  int h = rem >> 5, b = rem & 31;
  int bh = b*NHEAD + h;
  int r0 = qt*64;

  __shared__ __align__(16) u16 Ks[64][72];
  __shared__ __align__(16) u16 Vs[64][72];
  __shared__ __align__(16) u16 Rs[64][72];
  __shared__ __align__(16) u16 Pw[4][16][72];

  int tx = threadIdx.x, wave = tx>>6, lane = tx&63;
  int lcol = lane & 15;
  int quad = lane >> 4;
  int rw0 = r0 + wave*16;

  bf16x8 aq0 = {0,0,0,0,0,0,0,0}, aq1 = {0,0,0,0,0,0,0,0};
  {
    int qrow = rw0 + lcol;
    if(qrow < NTOK){
      const u16* qp = q + ((size_t)bh*NTOK + qrow)*HDIM + quad*8;
      aq0 = *(const bf16x8*)(qp);
      aq1 = *(const bf16x8*)(qp + 32);
    }
  }

  f32x4 o[4];
  #pragma unroll
  for(int j=0;j<4;j++){ f32x4 z={0.f,0.f,0.f,0.f}; o[j]=z; }
  float lpart[4] = {0.f,0.f,0.f,0.f};   // per-lane partial softmax mass

  int sr = tx>>3, sc = (tx&7)*8;

  const u16* kbase = k  + (size_t)bh*NTOK*HDIM;
  const u16* vbase = vt + (size_t)bh*HDIM*VST;
  const u16* rbase = rpb + ((size_t)h*NTOK + r0)*RST;

  for(int kt=0; kt<10; kt++){
    int key0 = kt*TK;
    *(bf16x8*)(&Ks[sr][sc])    = *(const bf16x8*)(kbase + (size_t)(key0+sr)*HDIM + sc);
    *(bf16x8*)(&Ks[32+sr][sc]) = *(const bf16x8*)(kbase + (size_t)(key0+32+sr)*HDIM + sc);
    *(bf16x8*)(&Vs[sr][sc])    = *(const bf16x8*)(vbase + (size_t)sr*VST + key0 + sc);
    *(bf16x8*)(&Vs[32+sr][sc]) = *(const bf16x8*)(vbase + (size_t)(32+sr)*VST + key0 + sc);
    *(bf16x8*)(&Rs[sr][sc])    = *(const bf16x8*)(rbase + (size_t)sr*RST + key0 + sc);
    *(bf16x8*)(&Rs[32+sr][sc]) = *(const bf16x8*)(rbase + (size_t)(32+sr)*RST + key0 + sc);
    __syncthreads();

    f32x4 s[4];
    #pragma unroll
    for(int c=0;c<4;c++){
      f32x4 z = {0.f,0.f,0.f,0.f};
      bf16x8 kb0 = *(const bf16x8*)(&Ks[16*c+lcol][quad*8]);
      bf16x8 kb1 = *(const bf16x8*)(&Ks[16*c+lcol][32+quad*8]);
      z = __builtin_amdgcn_mfma_f32_16x16x32_bf16(aq0, kb0, z, 0,0,0);
      z = __builtin_amdgcn_mfma_f32_16x16x32_bf16(aq1, kb1, z, 0,0,0);
      s[c] = z;
    }

    #pragma unroll
    for(int rr=0; rr<4; rr++){
      int qloc = wave*16 + quad*4 + rr;
      #pragma unroll
      for(int c=0;c<4;c++){
        int key = key0 + 16*c + lcol;
        float sv = (key < NTOK) ? s[c][rr] + bf2f(Rs[qloc][16*c+lcol]) : -1e30f;
        float pe = __expf(sv - SOFF);
        lpart[rr] += pe;
        Pw[wave][quad*4+rr][16*c+lcol] = f2bf(pe);
      }
    }
    bf16x8 ap0 = *(const bf16x8*)(&Pw[wave][lcol][quad*8]);
    bf16x8 ap1 = *(const bf16x8*)(&Pw[wave][lcol][32+quad*8]);
    #pragma unroll
    for(int j=0;j<4;j++){
      bf16x8 vb0 = *(const bf16x8*)(&Vs[16*j+lcol][quad*8]);
      bf16x8 vb1 = *(const bf16x8*)(&Vs[16*j+lcol][32+quad*8]);
      o[j] = __builtin_amdgcn_mfma_f32_16x16x32_bf16(ap0, vb0, o[j], 0,0,0);
      o[j] = __builtin_amdgcn_mfma_f32_16x16x32_bf16(ap1, vb1, o[j], 0,0,0);
    }
    __syncthreads();
  }

  // reduce softmax mass across the 16 lanes of each quad, then normalize
  #pragma unroll
  for(int rr=0;rr<4;rr++){
    float ts = lpart[rr];
    ts += __shfl_xor(ts, 1);
    ts += __shfl_xor(ts, 2);
    ts += __shfl_xor(ts, 4);
    ts += __shfl_xor(ts, 8);
    lpart[rr] = ts;
  }
  #pragma unroll
  for(int rr=0;rr<4;rr++){
    int n = rw0 + quad*4 + rr;
    if(n >= NTOK) continue;
    float inv = 1.0f / lpart[rr];
    u16* op = out + ((size_t)b*NTOK + n)*DIM + h*HDIM;
    #pragma unroll
    for(int j=0;j<4;j++)
      op[16*j + lcol] = f2bf(o[j][rr]*inv);
  }
}

extern "C" void kernel_launch(void* const* d_in, const int* in_sizes, int n_in,
                              void* d_out, int out_size, void* d_ws, size_t ws_size,
                              hipStream_t stream)
{
  const float* x      = (const float*)d_in[0];
  const float* n1g    = (const float*)d_in[1];
  const float* n1b    = (const float*)d_in[2];
  const float* qkvw   = (const float*)d_in[3];
  const float* qbias  = (const float*)d_in[4];
  const float* vbias  = (const float*)d_in[5];
  const float* rpbt   = (const float*)d_in[6];
  const float* projw  = (const float*)d_in[7];
  const float* projb  = (const float*)d_in[8];
  const float* n2g    = (const float*)d_in[9];
  const float* n2b    = (const float*)d_in[10];
  const float* fc1w   = (const float*)d_in[11];
  const float* fc1b   = (const float*)d_in[12];
  const float* fc2w   = (const float*)d_in[13];
  const float* fc2b   = (const float*)d_in[14];
  const int*   relidx = (const int*)d_in[15];

  char* ws = (char*)d_ws;
  const size_t WQ_OFF  = 0;
  const size_t WP_OFF  = 3538944;
  const size_t W1_OFF  = 4718592;
  const size_t W2_OFF  = 9437184;
  const size_t RPB_OFF = 14155776;
  const size_t H_OFF   = 30136576;
  const size_t Q_OFF   = H_OFF + 28360704;
  const size_t K_OFF   = Q_OFF + 28360704;
  const size_t V_OFF   = K_OFF + 28360704;
  const size_t ATT_OFF = V_OFF + 28704896;
  const size_t X1_OFF  = ATT_OFF + 28360704;
  const size_t M_OFF   = H_OFF;
  const size_t H2_OFF  = ATT_OFF;

  u16* wq   = (u16*)(ws + WQ_OFF);
  u16* wp   = (u16*)(ws + WP_OFF);
  u16* w1   = (u16*)(ws + W1_OFF);
  u16* w2   = (u16*)(ws + W2_OFF);
  u16* rpbb = (u16*)(ws + RPB_OFF);
  u16* hb   = (u16*)(ws + H_OFF);
  u16* qbuf = (u16*)(ws + Q_OFF);
  u16* kbuf = (u16*)(ws + K_OFF);
  u16* vbuf = (u16*)(ws + V_OFF);
  u16* attb = (u16*)(ws + ATT_OFF);
  float* x1 = (float*)(ws + X1_OFF);
  u16* mbuf = (u16*)(ws + M_OFF);
  u16* h2   = (u16*)(ws + H2_OFF);
  float* outp = (float*)d_out;

  const int ncvt = 2304*768 + 768*768 + 3072*768 + 3072*768;
  cvt4_kernel<<<(ncvt+255)/256, 256, 0, stream>>>(qkvw, 2304*768, projw, 768*768,
                                                  fc1w, 3072*768, fc2w, 3072*768,
                                                  wq, wp, w1, w2);
  rpb_kernel<<<(NHEAD*NTOK*NTOK+255)/256, 256, 0, stream>>>(relidx, rpbt, rpbb);

  const int GRP = 8 * ((NRT + 7)/8);   // 152

  ln_kernel<<<ROWS, 256, 0, stream>>>(x, n1g, n1b, hb);
  gemm_kernel<0,18><<<GRP*18, 256, 0, stream>>>(hb, wq, ROWS, DIM, qbias, vbias,
                                                nullptr, nullptr, qbuf, kbuf, vbuf);
  fattn_kernel<<<10*384, 256, 0, stream>>>(qbuf, kbuf, vbuf, rpbb, attb);
  gemm_kernel<1,6><<<GRP*6, 256, 0, stream>>>(attb, wp, ROWS, DIM, projb, nullptr,
                                              x, x1, nullptr, nullptr, nullptr);
  ln_kernel<<<ROWS, 256, 0, stream>>>(x1, n2g, n2b, h2);
  gemm_kernel<2,24><<<GRP*24, 256, 0, stream>>>(h2, w1, ROWS, DIM, fc1b, nullptr,
                                                nullptr, nullptr, mbuf, nullptr, nullptr);
  gemm_kernel<3,6><<<GRP*6, 256, 0, stream>>>(mbuf, w2, ROWS, MLP, fc2b, nullptr,
                                              x1, outp, nullptr, nullptr, nullptr);
}